// Round 8
// baseline (1155.384 us; speedup 1.0000x reference)
//
#include <hip/hip_runtime.h>
#include <hip/hip_bf16.h>
#include <type_traits>

using u16 = unsigned short;

static constexpr int BG   = 16384;          // graphs
static constexpr int NPG  = 11;             // nodes per graph
static constexpr int NTOT = BG * NPG;       // 180224 nodes
static constexpr int EDG  = NTOT * 8;       // 1441792 edges

typedef __attribute__((ext_vector_type(8))) short short8;   // 8 bf16 (4 VGPRs)
typedef __attribute__((ext_vector_type(4))) float f32x4;

__device__ __forceinline__ u16 f2bf(float f) {              // RNE fp32->bf16
  unsigned u = __float_as_uint(f);
  return (u16)((u + 0x7FFFu + ((u >> 16) & 1u)) >> 16);
}
__device__ __forceinline__ float bf2f(u16 u) { return __uint_as_float(((unsigned)u) << 16); }
__device__ __forceinline__ unsigned pk(float a, float b) {
  return (unsigned)f2bf(a) | ((unsigned)f2bf(b) << 16);
}
__device__ __forceinline__ float fast_sig(float x) {        // rcp: ~1ulp, ok at bf16 out
  return __builtin_amdgcn_rcpf(1.f + __expf(-x));
}
__device__ __forceinline__ float fast_tanh(float x) {       // overflow-safe
  float a = fabsf(x);
  float e = __expf(-2.f * a);
  float t = (1.f - e) * __builtin_amdgcn_rcpf(1.f + e);
  return copysignf(t, x);
}

// ---------------------------------------------------------------------------
// Persistent fused LSTM, all 11 timesteps. 1024 threads = 16 waves (4/SIMD,
// hard cap 128 regs/wave).
// OPERAND-SWAPPED: D[n'][b] = Wp[n'][k] · Xcat[b][k]; n' = 4*unit + gate ->
// the 4 gates of one unit land in one lane's 4 acc regs (no exchange).
// TWO PASSES SPLIT BY BATCH-COLS (j): pass p covers j = 2p..2p+1.
//  * acc[4][2] = 32 AGPR live per pass -> no spill (R6-proven budget)
//  * LDS xf reads NOT duplicated across passes (each pass reads only its own
//    j's) -> total LDS A-reads = merged-sweep level, half of R6's i-split
//  * wf (Wp) loads double, but Wp is L2-resident (1 MB) -> negligible
// LDS bank fixes (R7-proven: conflicts 2.8e7 -> 2.2e6):
//  * read/write swizzle f(r) = (r>>1)&3 (8 bank-groups hit 2x per 16 lanes)
//  * CHUNK = 2056 u16 (+16B pad) de-aliases chunk strides
// bias in LDS (reg relief). Ah double-buffered; 2 __syncthreads per step.
// LDS = 100.4 KB; grid 256 = 1 block/CU.
// ---------------------------------------------------------------------------
__global__ __launch_bounds__(1024, 4) void lstm_all(const float* __restrict__ feat,
                                                    u16* __restrict__ h,
                                                    const u16* __restrict__ Wp,
                                                    const float* __restrict__ biasP) {
  constexpr int CHUNK = 2056;             // 2048 data + 8 pad u16
  __shared__ u16 Ax[8 * CHUNK];           // x-part tile (this step)
  __shared__ u16 Ah[2][8 * CHUNK];        // h-part tiles, ping-pong per step
  __shared__ float bLds[1024];            // permuted bias
  const int tid  = threadIdx.x;
  const int lane = tid & 63;
  const int wave = tid >> 6;       // 0..15
  const int q = lane >> 4;
  const int l = lane & 15;
  const int row0 = blockIdx.x * 64;

  bLds[tid] = biasP[tid];
  // zero Ah[0] (read at t=0), incl. pads
  for (int i = tid; i < 8 * CHUNK / 2; i += 1024) ((unsigned*)Ah[0])[i] = 0u;

  float creg[4][4];                // cell state: (unit-frag i, batch-col j)
  #pragma unroll
  for (int i = 0; i < 4; ++i)
    #pragma unroll
    for (int j = 0; j < 4; ++j) creg[i][j] = 0.f;

  // per-lane Wp (A-operand) gather base: row n' = wave*64 + l, k-sub q
  const u16* wpA = Wp + (size_t)(wave * 64 + l) * 512 + q * 8;

  for (int t = 0; t < NPG; ++t) {
    const u16* AhR = Ah[t & 1];          // read buffer (prev step's h)
    u16*       AhW = Ah[(t + 1) & 1];    // write buffer (this step's h)

    // ---- stage Xcat x-part (64 x 256 fp32 -> bf16 swizzled B layout) ----
    #pragma unroll
    for (int p = 0; p < 2; ++p) {
      const int idx = p * 1024 + tid;      // 0..2047 8-elem chunks
      const int sr = idx >> 5;             // batch row 0..63
      const int cc = idx & 31;             // chunk within 256 k
      const int kk = cc >> 2, s2 = cc & 3;
      const float* fp = feat + (size_t)(row0 + sr) * 2816 + t * 256 + cc * 8;
      float4 f0 = *(const float4*)fp;
      float4 f1 = *(const float4*)(fp + 4);
      uint4 v;
      v.x = pk(f0.x, f0.y); v.y = pk(f0.z, f0.w);
      v.z = pk(f1.x, f1.y); v.w = pk(f1.z, f1.w);
      *(uint4*)&Ax[kk * CHUNK + (((sr << 2) + (s2 ^ ((sr >> 1) & 3)))) * 8] = v;
    }
    __syncthreads();   // Ax + bLds staged; prev-step AhW writes visible

    #pragma unroll
    for (int p = 0; p < 2; ++p) {        // two passes over batch cols
      f32x4 acc[4][2] = {};
      // ---- x half: chunks 0..7 from Ax ----
      #pragma unroll 4
      for (int kk = 0; kk < 8; ++kk) {
        const u16* Bsrc = &Ax[kk * CHUNK];
        short8 wf[4];
        #pragma unroll
        for (int i = 0; i < 4; ++i)
          wf[i] = *(const short8*)(wpA + (size_t)(i * 16) * 512 + kk * 32);
        #pragma unroll
        for (int jj = 0; jj < 2; ++jj) {
          const int b = (p * 2 + jj) * 16 + l;
          short8 xf = *(const short8*)&Bsrc[(((b << 2) + (q ^ ((b >> 1) & 3)))) * 8];
          #pragma unroll
          for (int i = 0; i < 4; ++i)
            acc[i][jj] = __builtin_amdgcn_mfma_f32_16x16x32_bf16(wf[i], xf, acc[i][jj], 0, 0, 0);
        }
      }
      // ---- h half: chunks 8..15 from AhR ----
      #pragma unroll 4
      for (int kk = 0; kk < 8; ++kk) {
        const u16* Bsrc = &AhR[kk * CHUNK];
        short8 wf[4];
        #pragma unroll
        for (int i = 0; i < 4; ++i)
          wf[i] = *(const short8*)(wpA + (size_t)(i * 16) * 512 + (kk + 8) * 32);
        #pragma unroll
        for (int jj = 0; jj < 2; ++jj) {
          const int b = (p * 2 + jj) * 16 + l;
          short8 xf = *(const short8*)&Bsrc[(((b << 2) + (q ^ ((b >> 1) & 3)))) * 8];
          #pragma unroll
          for (int i = 0; i < 4; ++i)
            acc[i][jj] = __builtin_amdgcn_mfma_f32_16x16x32_bf16(wf[i], xf, acc[i][jj], 0, 0, 0);
        }
      }
      // ---- epilogue (this pass): LSTM pointwise; h -> AhW (swizzled) ----
      #pragma unroll
      for (int i = 0; i < 4; ++i) {
        const int u = wave * 16 + i * 4 + q;             // unit index 0..255
        const float4 bb = *(const float4*)&bLds[u * 4];  // broadcast in q-group
        const int kk2 = u >> 5, c2 = (u >> 3) & 3, e = u & 7;
        #pragma unroll
        for (int jj = 0; jj < 2; ++jj) {
          const int j = p * 2 + jj;
          const float gi = acc[i][jj][0] + bb.x;
          const float gf = acc[i][jj][1] + bb.y;
          const float gg = acc[i][jj][2] + bb.z;
          const float go = acc[i][jj][3] + bb.w;
          const float cn = fast_sig(gf) * creg[i][j] + fast_sig(gi) * fast_tanh(gg);
          creg[i][j] = cn;
          const float hv = fast_sig(go) * fast_tanh(cn);
          const u16 hb = f2bf(hv);
          const int b = j * 16 + l;                      // batch row (local)
          AhW[kk2 * CHUNK + (((b << 2) + (c2 ^ ((b >> 1) & 3)))) * 8 + e] = hb;
          if (t == NPG - 1) h[(size_t)(row0 + b) * 256 + u] = hb;
        }
      }
    }
    __syncthreads();   // Ax/AhR reads + AhW writes done before next stage
  }
}

// ---------------------------------------------------------------------------
// MFMA GEMM: C[M,N] = A[M,K] @ Bt[N,K]^T.  BM=128, BN=256, BK=32, 512 thr.
// AMODE 0: A fp32 row-major (stride K). AMODE 1: A bf16 row-major; in-place
// C==A safe (full row read before epilogue write, full N per row-block).
// ---------------------------------------------------------------------------
template<int AMODE, typename TC>
__global__ __launch_bounds__(512) void gemm_mfma(const float* __restrict__ Af,
                                                 const u16* Ab,
                                                 const u16* __restrict__ Bt,
                                                 TC* C, int N, int K) {
  __shared__ u16 Alds[128 * 32];
  __shared__ u16 Blds[256 * 32];
  const int tid  = threadIdx.x;
  const int lane = tid & 63;
  const int wave = tid >> 6;
  const int q = lane >> 4;
  const int l = lane & 15;
  const int wm = (wave >> 2) * 64;
  const int wn = (wave & 3) * 64;
  const int row0 = blockIdx.y * 128;
  const int col0 = blockIdx.x * 256;

  f32x4 acc[4][4] = {};
  const int sr = tid >> 2;
  const int sq = tid & 3;
  const int aslot = sq ^ (sr & 3);

  for (int k0 = 0; k0 < K; k0 += 32) {
    {
      uint4 v;
      if constexpr (AMODE == 0) {
        const float* p = Af + (size_t)(row0 + sr) * K + k0 + sq * 8;
        float4 f0 = *(const float4*)p;
        float4 f1 = *(const float4*)(p + 4);
        v.x = pk(f0.x, f0.y); v.y = pk(f0.z, f0.w);
        v.z = pk(f1.x, f1.y); v.w = pk(f1.z, f1.w);
      } else {
        v = *(const uint4*)(Ab + (size_t)(row0 + sr) * K + k0 + sq * 8);
      }
      *(uint4*)&Alds[(((sr << 2) + aslot)) << 3] = v;
    }
    #pragma unroll
    for (int i = 0; i < 2; ++i) {
      const int n = sr + i * 128;
      const int slot = sq ^ (n & 3);
      uint4 v = *(const uint4*)(Bt + (size_t)(col0 + n) * K + k0 + sq * 8);
      *(uint4*)&Blds[(((n << 2) + slot)) << 3] = v;
    }
    __syncthreads();
    short8 af[4], bfr[4];
    #pragma unroll
    for (int i = 0; i < 4; ++i) {
      const int r = wm + i * 16 + l;
      af[i] = *(const short8*)&Alds[(((r << 2) + (q ^ (r & 3)))) << 3];
    }
    #pragma unroll
    for (int j = 0; j < 4; ++j) {
      const int n = wn + j * 16 + l;
      bfr[j] = *(const short8*)&Blds[(((n << 2) + (q ^ (n & 3)))) << 3];
    }
    #pragma unroll
    for (int i = 0; i < 4; ++i)
      #pragma unroll
      for (int j = 0; j < 4; ++j)
        acc[i][j] = __builtin_amdgcn_mfma_f32_16x16x32_bf16(af[i], bfr[j], acc[i][j], 0, 0, 0);
    __syncthreads();
  }
  #pragma unroll
  for (int i = 0; i < 4; ++i) {
    #pragma unroll
    for (int j = 0; j < 4; ++j) {
      #pragma unroll
      for (int r = 0; r < 4; ++r) {
        const int row = row0 + wm + i * 16 + q * 4 + r;
        const int col = col0 + wn + j * 16 + l;
        if constexpr (std::is_same<TC, float>::value)
          C[(size_t)row * N + col] = acc[i][j][r];
        else
          C[(size_t)row * N + col] = f2bf(acc[i][j][r]);
      }
    }
  }
}

// ---------------- weight prep ----------------
// Wp[n'][k], n' = 4*unit + gate; also builds permuted combined bias.
__global__ __launch_bounds__(256) void k_prep_lstm_w(const float* __restrict__ Wih,
                                                     const float* __restrict__ Whh,
                                                     const float* __restrict__ bih,
                                                     const float* __restrict__ bhh,
                                                     u16* __restrict__ Wp,
                                                     float* __restrict__ biasP) {
  const int idx = blockIdx.x * 256 + threadIdx.x;   // 1024*512
  const int np = idx >> 9, k = idx & 511;
  const int u = np >> 2, g = np & 3;
  const int n = g * 256 + u;
  const float v = (k < 256) ? Wih[n * 256 + k] : Whh[n * 256 + (k - 256)];
  Wp[idx] = f2bf(v);
  if (k == 0) biasP[np] = bih[n] + bhh[n];
}

__global__ __launch_bounds__(256) void k_transpose_w(const float* __restrict__ W,
                                                     u16* __restrict__ Wt) {
  const int idx = blockIdx.x * 256 + threadIdx.x;   // 256*256, Wt[n][k]=W[k][n]
  const int n = idx >> 8, k = idx & 255;
  Wt[idx] = f2bf(W[k * 256 + n]);
}

// out_ff[b,:2] = (h[b] @ Wf1 + bf1) @ Wf2 + bf2 ; 16 rows/block, 256 thr
__global__ __launch_bounds__(256) void ff_kernel(const u16* __restrict__ h,
                                                 const float* __restrict__ Wf1,
                                                 const float* __restrict__ bf1,
                                                 const float* __restrict__ Wf2,
                                                 const float* __restrict__ bf2,
                                                 float* __restrict__ ffout) {
  __shared__ float hrow[16][256];
  __shared__ float tmp[16][64];
  const int tid = threadIdx.x;
  const int b0 = blockIdx.x * 16;
  for (int i = tid; i < 16 * 256; i += 256)
    hrow[i >> 8][i & 255] = bf2f(h[(size_t)(b0 + (i >> 8)) * 256 + (i & 255)]);
  __syncthreads();
  const int n = tid & 63, r = tid >> 6;   // r 0..3 -> rows r, r+4, r+8, r+12
  float a0 = bf1[n], a1 = a0, a2 = a0, a3 = a0;
  #pragma unroll 8
  for (int k = 0; k < 256; ++k) {
    const float w = Wf1[k * 64 + n];
    a0 += hrow[r][k] * w;
    a1 += hrow[r + 4][k] * w;
    a2 += hrow[r + 8][k] * w;
    a3 += hrow[r + 12][k] * w;
  }
  tmp[r][n] = a0; tmp[r + 4][n] = a1; tmp[r + 8][n] = a2; tmp[r + 12][n] = a3;
  __syncthreads();
  if (tid < 32) {
    const int rr = tid >> 1, jj = tid & 1;
    float o = bf2[jj];
    #pragma unroll
    for (int k2 = 0; k2 < 64; ++k2) o += tmp[rr][k2] * Wf2[k2 * 2 + jj];
    ffout[(size_t)(b0 + rr) * 2 + jj] = o;
  }
}

// ---------------- GCN graph-operator precompute (fused, no global atomics) --
// Edges are grouped by graph (e = g*88 + j), so degrees and M are block-local.
__global__ __launch_bounds__(256) void k_graph_mats(const int* __restrict__ src,
                                                    const int* __restrict__ dst,
                                                    float* __restrict__ Mg) {
  constexpr int GPB = 32;                 // graphs per block
  __shared__ float Ms[GPB * 121];
  __shared__ float od[GPB * NPG];
  __shared__ float idg[GPB * NPG];
  const int tid = threadIdx.x;
  const int g0 = blockIdx.x * GPB;
  for (int i = tid; i < GPB * 121; i += 256) Ms[i] = 0.f;
  for (int i = tid; i < GPB * NPG; i += 256) { od[i] = 0.f; idg[i] = 0.f; }
  __syncthreads();
  const int ebase = g0 * 88;              // 32*88 = 2816 = 11*256 edges
  int ls[11], ld[11];
  #pragma unroll
  for (int i = 0; i < 11; ++i) {
    const int e = ebase + tid + i * 256;
    const int s = src[e], d = dst[e];
    const int g = s / NPG;                // src and dst share the graph
    const int gl = g - g0;
    ls[i] = gl * NPG + (s - g * NPG);
    ld[i] = gl * NPG + (d - g * NPG);
    atomicAdd(&od[ls[i]], 1.f);
    atomicAdd(&idg[ld[i]], 1.f);
  }
  __syncthreads();
  for (int i = tid; i < GPB * NPG; i += 256) {
    od[i]  = rsqrtf(fmaxf(od[i], 1.f));
    idg[i] = rsqrtf(fmaxf(idg[i], 1.f));
  }
  __syncthreads();
  #pragma unroll
  for (int i = 0; i < 11; ++i) {
    const int gl  = ls[i] / NPG;
    const int lsl = ls[i] - gl * NPG;
    const int ldl = ld[i] - gl * NPG;
    atomicAdd(&Ms[gl * 121 + ldl * NPG + lsl], od[ls[i]] * idg[ld[i]]);
  }
  __syncthreads();
  for (int i = tid; i < GPB * 121; i += 256) Mg[(size_t)g0 * 121 + i] = Ms[i];
}

// X[g,d,:] = act( sum_s M_g[d][s] * Y[g,s,:] + bias )  in-place safe
template<int ACT>
__global__ __launch_bounds__(256) void k_mapply(const u16* __restrict__ Y,
                                                const float* __restrict__ Mg,
                                                const float* __restrict__ bias,
                                                u16* __restrict__ X) {
  __shared__ float Ms[121];
  const int g = blockIdx.x, c = threadIdx.x;
  if (c < 121) Ms[c] = Mg[(size_t)g * 121 + c];
  float y[NPG];
  const u16* yp = Y + (size_t)g * NPG * 256 + c;
  #pragma unroll
  for (int s = 0; s < NPG; ++s) y[s] = bf2f(yp[s * 256]);
  const float bc_ = bias[c];
  __syncthreads();
  u16* xp = X + (size_t)g * NPG * 256 + c;
  #pragma unroll
  for (int d = 0; d < NPG; ++d) {
    float z = bc_;
    #pragma unroll
    for (int s = 0; s < NPG; ++s) z += Ms[d * NPG + s] * y[s];
    if (ACT == 0) z = fmaxf(z, 0.f); else z = fast_tanh(z);
    xp[d * 256] = f2bf(z);
  }
}

// Y3[N,8] = X[N,256] @ W3[256,8]
__global__ __launch_bounds__(256) void k_gemm3(const u16* __restrict__ X,
                                               const float* __restrict__ W3,
                                               float* __restrict__ Y3) {
  __shared__ float W3s[2048];
  const int tid = threadIdx.x;
  for (int i = tid; i < 2048; i += 256) W3s[i] = W3[i];
  __syncthreads();
  const int r = tid >> 3, j = tid & 7;
  const int row = blockIdx.x * 32 + r;
  const u16* xp = X + (size_t)row * 256;
  float acc = 0.f;
  #pragma unroll 4
  for (int k = 0; k < 256; ++k) acc += bf2f(xp[k]) * W3s[k * 8 + j];
  Y3[(size_t)row * 8 + j] = acc;
}

// layer3 M-apply + relu + mean + classify + add LSTM ff output
__global__ __launch_bounds__(256) void k_final(const float* __restrict__ Y3,
                                               const float* __restrict__ Mg,
                                               const float* __restrict__ b3,
                                               const float* __restrict__ Wc,
                                               const float* __restrict__ bc,
                                               const float* __restrict__ ffout,
                                               float* __restrict__ out) {
  __shared__ float Ms[32][121];
  __shared__ float hg[32][8];
  const int tid = threadIdx.x;
  const int g0 = blockIdx.x * 32;
  for (int i = tid; i < 32 * 121; i += 256) Ms[i / 121][i % 121] = Mg[(size_t)g0 * 121 + i];
  const int gl = tid >> 3, j = tid & 7;
  const int g = g0 + gl;
  float y[NPG];
  #pragma unroll
  for (int s = 0; s < NPG; ++s) y[s] = Y3[((size_t)g * NPG + s) * 8 + j];
  __syncthreads();
  const float bj = b3[j];
  float accm = 0.f;
  #pragma unroll
  for (int d = 0; d < NPG; ++d) {
    float z = bj;
    #pragma unroll
    for (int s = 0; s < NPG; ++s) z += Ms[gl][d * NPG + s] * y[s];
    accm += fmaxf(z, 0.f);
  }
  hg[gl][j] = accm * (1.0f / 11.0f);
  __syncthreads();
  if (j < 2) {
    float o = bc[j];
    #pragma unroll
    for (int qq = 0; qq < 8; ++qq) o += hg[gl][qq] * Wc[qq * 2 + j];
    out[(size_t)g * 2 + j] = o + ffout[(size_t)g * 2 + j];
  }
}

// ---------------------------------------------------------------------------
extern "C" void kernel_launch(void* const* d_in, const int* in_sizes, int n_in,
                              void* d_out, int out_size, void* d_ws, size_t ws_size,
                              hipStream_t stream) {
  (void)in_sizes; (void)n_in; (void)out_size; (void)ws_size;
  const float* feature = (const float*)d_in[0];
  const int*   src     = (const int*)d_in[1];
  const int*   dst     = (const int*)d_in[2];
  const float* W1  = (const float*)d_in[3];
  const float* b1  = (const float*)d_in[4];
  const float* W2  = (const float*)d_in[5];
  const float* b2  = (const float*)d_in[6];
  const float* W3  = (const float*)d_in[7];
  const float* b3  = (const float*)d_in[8];
  const float* Wih = (const float*)d_in[9];
  const float* Whh = (const float*)d_in[10];
  const float* bih = (const float*)d_in[11];
  const float* bhh = (const float*)d_in[12];
  const float* Wf1 = (const float*)d_in[13];
  const float* bf1 = (const float*)d_in[14];
  const float* Wf2 = (const float*)d_in[15];
  const float* bf2 = (const float*)d_in[16];
  const float* Wc  = (const float*)d_in[17];
  const float* bc  = (const float*)d_in[18];
  float* out = (float*)d_out;

  // ---- workspace layout: 107,417,600 B total (unchanged from passing R2) ---
  char* ws = (char*)d_ws;
  float* ffout = (float*)ws;                        //    131,072
  u16*   Wp    = (u16*)(ws + 131072);               //  1,048,576
  u16*   Wt1   = (u16*)(ws + 1179648);              //    131,072
  u16*   Wt2   = (u16*)(ws + 1310720);              //    131,072
  float* biasP = (float*)(ws + 1441792);            //      4,096
  float* Mg    = (float*)(ws + 1445888);            //  7,929,856
  u16*   Abuf  = (u16*)(ws + 9375744);              // 92,274,688
  u16*   hbuf  = (u16*)(ws + 9375744);              //  8,388,608 (alias, LSTM phase only)
  float* Y3    = (float*)(ws + 101650432);          //  5,767,168

  // ---- weight prep ----
  k_prep_lstm_w<<<2048, 256, 0, stream>>>(Wih, Whh, bih, bhh, Wp, biasP);
  k_transpose_w<<<256, 256, 0, stream>>>(W1, Wt1);
  k_transpose_w<<<256, 256, 0, stream>>>(W2, Wt2);

  // ================= LSTM branch (single persistent kernel) =================
  lstm_all<<<BG / 64, 1024, 0, stream>>>(feature, hbuf, Wp, biasP);
  ff_kernel<<<BG / 16, 256, 0, stream>>>(hbuf, Wf1, bf1, Wf2, bf2, ffout);
  // hbuf dead from here on; Abuf may now overwrite it.

  // ================= GCN branch =================
  k_graph_mats<<<BG / 32, 256, 0, stream>>>(src, dst, Mg);

  // layer 1: GEMM (fp32 A -> bf16) + in-place graph mix + relu
  gemm_mfma<0, u16><<<dim3(1, NTOT / 128), 512, 0, stream>>>(feature, nullptr, Wt1, Abuf, 256, 256);
  k_mapply<0><<<BG, 256, 0, stream>>>(Abuf, Mg, b1, Abuf);

  // layer 2: in-place GEMM (full N covered per row-block) + mix + tanh
  gemm_mfma<1, u16><<<dim3(1, NTOT / 128), 512, 0, stream>>>(nullptr, Abuf, Wt2, Abuf, 256, 256);
  k_mapply<1><<<BG, 256, 0, stream>>>(Abuf, Mg, b2, Abuf);

  // layer 3 + pooling + classifier + combine
  k_gemm3<<<NTOT / 32, 256, 0, stream>>>(Abuf, W3, Y3);
  k_final<<<BG / 32, 256, 0, stream>>>(Y3, Mg, b3, Wc, bc, ffout, out);
}

// Round 9
// 727.552 us; speedup vs baseline: 1.5880x; 1.5880x over previous
//
#include <hip/hip_runtime.h>
#include <hip/hip_bf16.h>
#include <type_traits>

using u16 = unsigned short;

static constexpr int BG   = 16384;          // graphs
static constexpr int NPG  = 11;             // nodes per graph
static constexpr int NTOT = BG * NPG;       // 180224 nodes
static constexpr int EDG  = NTOT * 8;       // 1441792 edges

typedef __attribute__((ext_vector_type(8))) short short8;   // 8 bf16 (4 VGPRs)
typedef __attribute__((ext_vector_type(4))) float f32x4;

__device__ __forceinline__ u16 f2bf(float f) {              // RNE fp32->bf16
  unsigned u = __float_as_uint(f);
  return (u16)((u + 0x7FFFu + ((u >> 16) & 1u)) >> 16);
}
__device__ __forceinline__ float bf2f(u16 u) { return __uint_as_float(((unsigned)u) << 16); }
__device__ __forceinline__ unsigned pk(float a, float b) {
  return (unsigned)f2bf(a) | ((unsigned)f2bf(b) << 16);
}
__device__ __forceinline__ float fast_sig(float x) {        // rcp: ~1ulp, ok at bf16 out
  return __builtin_amdgcn_rcpf(1.f + __expf(-x));
}
__device__ __forceinline__ float fast_tanh(float x) {       // overflow-safe
  float a = fabsf(x);
  float e = __expf(-2.f * a);
  float t = (1.f - e) * __builtin_amdgcn_rcpf(1.f + e);
  return copysignf(t, x);
}

// ---------------------------------------------------------------------------
// Persistent fused LSTM, all 11 timesteps. 1024 threads = 16 waves (4/SIMD,
// hard cap 128 regs/wave).
// OPERAND-SWAPPED: D[n'][b] = W[n'][k] · Xcat[b][k]; n' = 4*unit + gate ->
// the 4 gates of one unit land in one lane's 4 acc regs (no exchange).
// R8 A/B LESSON: one scattered Wp L2 gather costs ~8x one LDS read; gathers
// dominated R6-R8. FIX: weights pre-permuted into MFMA-FRAGMENT ORDER (wfP):
// a wave's wf load is one CONTIGUOUS 1KB stream (lane*16B), not a 64KB-span
// gather -> sequential L2 BW + L1 hits, no over-fetch.
// TWO PASSES SPLIT BY UNIT-FRAGS (R6-proven no-spill): pass p covers frags
// f = 2p..2p+1 -> acc[2][4] = 32 AGPR live; wf loads NOT duplicated across
// passes (64 coalesced loads/step/wave total); xf LDS reads double (cheap).
// LDS bank fixes (R7-proven: conflicts 2.8e7 -> 2.2e6): read/write swizzle
// f(r)=(r>>1)&3 + CHUNK=2056 pad. bias in LDS. Ah double-buffered;
// 2 __syncthreads per step. LDS = 100.4 KB; grid 256 = 1 block/CU.
// ---------------------------------------------------------------------------
__global__ __launch_bounds__(1024, 4) void lstm_all(const float* __restrict__ feat,
                                                    u16* __restrict__ h,
                                                    const u16* __restrict__ WfP,
                                                    const float* __restrict__ biasP) {
  constexpr int CHUNK = 2056;             // 2048 data + 8 pad u16
  __shared__ u16 Ax[8 * CHUNK];           // x-part tile (this step)
  __shared__ u16 Ah[2][8 * CHUNK];        // h-part tiles, ping-pong per step
  __shared__ float bLds[1024];            // permuted bias
  const int tid  = threadIdx.x;
  const int lane = tid & 63;
  const int wave = tid >> 6;       // 0..15
  const int q = lane >> 4;
  const int l = lane & 15;
  const int row0 = blockIdx.x * 64;

  bLds[tid] = biasP[tid];
  // zero Ah[0] (read at t=0), incl. pads
  for (int i = tid; i < 8 * CHUNK / 2; i += 1024) ((unsigned*)Ah[0])[i] = 0u;

  float creg[2][2][4];             // cell state: [pass][unit-frag i][batch-col j]
  #pragma unroll
  for (int p = 0; p < 2; ++p)
    #pragma unroll
    for (int i = 0; i < 2; ++i)
      #pragma unroll
      for (int j = 0; j < 4; ++j) creg[p][i][j] = 0.f;

  // per-lane coalesced fragment base: wave block + lane*16B
  const u16* wfBase = WfP + ((size_t)wave << 15) + (lane << 3);

  for (int t = 0; t < NPG; ++t) {
    const u16* AhR = Ah[t & 1];          // read buffer (prev step's h)
    u16*       AhW = Ah[(t + 1) & 1];    // write buffer (this step's h)

    // ---- stage Xcat x-part (64 x 256 fp32 -> bf16 swizzled B layout) ----
    #pragma unroll
    for (int p = 0; p < 2; ++p) {
      const int idx = p * 1024 + tid;      // 0..2047 8-elem chunks
      const int sr = idx >> 5;             // batch row 0..63
      const int cc = idx & 31;             // chunk within 256 k
      const int kk = cc >> 2, s2 = cc & 3;
      const float* fp = feat + (size_t)(row0 + sr) * 2816 + t * 256 + cc * 8;
      float4 f0 = *(const float4*)fp;
      float4 f1 = *(const float4*)(fp + 4);
      uint4 v;
      v.x = pk(f0.x, f0.y); v.y = pk(f0.z, f0.w);
      v.z = pk(f1.x, f1.y); v.w = pk(f1.z, f1.w);
      *(uint4*)&Ax[kk * CHUNK + (((sr << 2) + (s2 ^ ((sr >> 1) & 3)))) * 8] = v;
    }
    __syncthreads();   // Ax + bLds staged; prev-step AhW writes visible

    #pragma unroll
    for (int p = 0; p < 2; ++p) {        // two passes over unit-frag pairs
      f32x4 acc[2][4] = {};
      // ---- x half: chunks 0..7 from Ax ----
      #pragma unroll 4
      for (int kk = 0; kk < 8; ++kk) {
        const u16* Bsrc = &Ax[kk * CHUNK];
        short8 wf[2];
        #pragma unroll
        for (int i = 0; i < 2; ++i)
          wf[i] = *(const short8*)(wfBase + kk * 2048 + (p * 2 + i) * 512);
        #pragma unroll
        for (int j = 0; j < 4; ++j) {
          const int b = j * 16 + l;
          short8 xf = *(const short8*)&Bsrc[(((b << 2) + (q ^ ((b >> 1) & 3)))) * 8];
          #pragma unroll
          for (int i = 0; i < 2; ++i)
            acc[i][j] = __builtin_amdgcn_mfma_f32_16x16x32_bf16(wf[i], xf, acc[i][j], 0, 0, 0);
        }
      }
      // ---- h half: chunks 8..15 from AhR ----
      #pragma unroll 4
      for (int kk = 0; kk < 8; ++kk) {
        const u16* Bsrc = &AhR[kk * CHUNK];
        short8 wf[2];
        #pragma unroll
        for (int i = 0; i < 2; ++i)
          wf[i] = *(const short8*)(wfBase + (kk + 8) * 2048 + (p * 2 + i) * 512);
        #pragma unroll
        for (int j = 0; j < 4; ++j) {
          const int b = j * 16 + l;
          short8 xf = *(const short8*)&Bsrc[(((b << 2) + (q ^ ((b >> 1) & 3)))) * 8];
          #pragma unroll
          for (int i = 0; i < 2; ++i)
            acc[i][j] = __builtin_amdgcn_mfma_f32_16x16x32_bf16(wf[i], xf, acc[i][j], 0, 0, 0);
        }
      }
      // ---- epilogue (this pass): LSTM pointwise; h -> AhW (swizzled) ----
      #pragma unroll
      for (int i = 0; i < 2; ++i) {
        const int u = wave * 16 + (p * 2 + i) * 4 + q;    // unit index 0..255
        const float4 bb = *(const float4*)&bLds[u * 4];   // broadcast in q-group
        const int kk2 = u >> 5, c2 = (u >> 3) & 3, e = u & 7;
        #pragma unroll
        for (int j = 0; j < 4; ++j) {
          const float gi = acc[i][j][0] + bb.x;
          const float gf = acc[i][j][1] + bb.y;
          const float gg = acc[i][j][2] + bb.z;
          const float go = acc[i][j][3] + bb.w;
          const float cn = fast_sig(gf) * creg[p][i][j] + fast_sig(gi) * fast_tanh(gg);
          creg[p][i][j] = cn;
          const float hv = fast_sig(go) * fast_tanh(cn);
          const u16 hb = f2bf(hv);
          const int b = j * 16 + l;                       // batch row (local)
          AhW[kk2 * CHUNK + (((b << 2) + (c2 ^ ((b >> 1) & 3)))) * 8 + e] = hb;
          if (t == NPG - 1) h[(size_t)(row0 + b) * 256 + u] = hb;
        }
      }
    }
    __syncthreads();   // Ax/AhR reads + AhW writes done before next stage
  }
}

// ---------------------------------------------------------------------------
// MFMA GEMM: C[M,N] = A[M,K] @ Bt[N,K]^T.  BM=128, BN=256, BK=32, 512 thr.
// AMODE 0: A fp32 row-major (stride K). AMODE 1: A bf16 row-major; in-place
// C==A safe (full row read before epilogue write, full N per row-block).
// ---------------------------------------------------------------------------
template<int AMODE, typename TC>
__global__ __launch_bounds__(512) void gemm_mfma(const float* __restrict__ Af,
                                                 const u16* Ab,
                                                 const u16* __restrict__ Bt,
                                                 TC* C, int N, int K) {
  __shared__ u16 Alds[128 * 32];
  __shared__ u16 Blds[256 * 32];
  const int tid  = threadIdx.x;
  const int lane = tid & 63;
  const int wave = tid >> 6;
  const int q = lane >> 4;
  const int l = lane & 15;
  const int wm = (wave >> 2) * 64;
  const int wn = (wave & 3) * 64;
  const int row0 = blockIdx.y * 128;
  const int col0 = blockIdx.x * 256;

  f32x4 acc[4][4] = {};
  const int sr = tid >> 2;
  const int sq = tid & 3;
  const int aslot = sq ^ (sr & 3);

  for (int k0 = 0; k0 < K; k0 += 32) {
    {
      uint4 v;
      if constexpr (AMODE == 0) {
        const float* p = Af + (size_t)(row0 + sr) * K + k0 + sq * 8;
        float4 f0 = *(const float4*)p;
        float4 f1 = *(const float4*)(p + 4);
        v.x = pk(f0.x, f0.y); v.y = pk(f0.z, f0.w);
        v.z = pk(f1.x, f1.y); v.w = pk(f1.z, f1.w);
      } else {
        v = *(const uint4*)(Ab + (size_t)(row0 + sr) * K + k0 + sq * 8);
      }
      *(uint4*)&Alds[(((sr << 2) + aslot)) << 3] = v;
    }
    #pragma unroll
    for (int i = 0; i < 2; ++i) {
      const int n = sr + i * 128;
      const int slot = sq ^ (n & 3);
      uint4 v = *(const uint4*)(Bt + (size_t)(col0 + n) * K + k0 + sq * 8);
      *(uint4*)&Blds[(((n << 2) + slot)) << 3] = v;
    }
    __syncthreads();
    short8 af[4], bfr[4];
    #pragma unroll
    for (int i = 0; i < 4; ++i) {
      const int r = wm + i * 16 + l;
      af[i] = *(const short8*)&Alds[(((r << 2) + (q ^ (r & 3)))) << 3];
    }
    #pragma unroll
    for (int j = 0; j < 4; ++j) {
      const int n = wn + j * 16 + l;
      bfr[j] = *(const short8*)&Blds[(((n << 2) + (q ^ (n & 3)))) << 3];
    }
    #pragma unroll
    for (int i = 0; i < 4; ++i)
      #pragma unroll
      for (int j = 0; j < 4; ++j)
        acc[i][j] = __builtin_amdgcn_mfma_f32_16x16x32_bf16(af[i], bfr[j], acc[i][j], 0, 0, 0);
    __syncthreads();
  }
  #pragma unroll
  for (int i = 0; i < 4; ++i) {
    #pragma unroll
    for (int j = 0; j < 4; ++j) {
      #pragma unroll
      for (int r = 0; r < 4; ++r) {
        const int row = row0 + wm + i * 16 + q * 4 + r;
        const int col = col0 + wn + j * 16 + l;
        if constexpr (std::is_same<TC, float>::value)
          C[(size_t)row * N + col] = acc[i][j][r];
        else
          C[(size_t)row * N + col] = f2bf(acc[i][j][r]);
      }
    }
  }
}

// ---------------- weight prep ----------------
// WfP in MFMA-fragment order: element (w,kk,f,lane,e) at flat idx
// (((w*16+kk)*4+f)*64 + lane)*8 + e  equals  Wp[n'][k] with
// n' = w*64 + f*16 + (lane&15), k = kk*32 + (lane>>4)*8 + e, n' = 4*unit+gate.
// Also builds permuted combined bias.
__global__ __launch_bounds__(256) void k_prep_lstm_w(const float* __restrict__ Wih,
                                                     const float* __restrict__ Whh,
                                                     const float* __restrict__ bih,
                                                     const float* __restrict__ bhh,
                                                     u16* __restrict__ WfP,
                                                     float* __restrict__ biasP) {
  const int idx = blockIdx.x * 256 + threadIdx.x;   // 0..524287
  const int e = idx & 7;
  const int lane = (idx >> 3) & 63;
  const int chunk = idx >> 9;          // 0..1023
  const int f = chunk & 3;
  const int kk = (chunk >> 2) & 15;
  const int w = chunk >> 6;
  const int q = lane >> 4, l = lane & 15;
  const int np = w * 64 + f * 16 + l;  // n' = 4*unit + gate
  const int k = kk * 32 + q * 8 + e;
  const int u = np >> 2, g = np & 3;
  const int n = g * 256 + u;
  const float v = (k < 256) ? Wih[n * 256 + k] : Whh[n * 256 + (k - 256)];
  WfP[idx] = f2bf(v);
  if (k == 0) biasP[np] = bih[n] + bhh[n];
}

__global__ __launch_bounds__(256) void k_transpose_w(const float* __restrict__ W,
                                                     u16* __restrict__ Wt) {
  const int idx = blockIdx.x * 256 + threadIdx.x;   // 256*256, Wt[n][k]=W[k][n]
  const int n = idx >> 8, k = idx & 255;
  Wt[idx] = f2bf(W[k * 256 + n]);
}

// out_ff[b,:2] = (h[b] @ Wf1 + bf1) @ Wf2 + bf2 ; 16 rows/block, 256 thr
__global__ __launch_bounds__(256) void ff_kernel(const u16* __restrict__ h,
                                                 const float* __restrict__ Wf1,
                                                 const float* __restrict__ bf1,
                                                 const float* __restrict__ Wf2,
                                                 const float* __restrict__ bf2,
                                                 float* __restrict__ ffout) {
  __shared__ float hrow[16][256];
  __shared__ float tmp[16][64];
  const int tid = threadIdx.x;
  const int b0 = blockIdx.x * 16;
  for (int i = tid; i < 16 * 256; i += 256)
    hrow[i >> 8][i & 255] = bf2f(h[(size_t)(b0 + (i >> 8)) * 256 + (i & 255)]);
  __syncthreads();
  const int n = tid & 63, r = tid >> 6;   // r 0..3 -> rows r, r+4, r+8, r+12
  float a0 = bf1[n], a1 = a0, a2 = a0, a3 = a0;
  #pragma unroll 8
  for (int k = 0; k < 256; ++k) {
    const float w = Wf1[k * 64 + n];
    a0 += hrow[r][k] * w;
    a1 += hrow[r + 4][k] * w;
    a2 += hrow[r + 8][k] * w;
    a3 += hrow[r + 12][k] * w;
  }
  tmp[r][n] = a0; tmp[r + 4][n] = a1; tmp[r + 8][n] = a2; tmp[r + 12][n] = a3;
  __syncthreads();
  if (tid < 32) {
    const int rr = tid >> 1, jj = tid & 1;
    float o = bf2[jj];
    #pragma unroll
    for (int k2 = 0; k2 < 64; ++k2) o += tmp[rr][k2] * Wf2[k2 * 2 + jj];
    ffout[(size_t)(b0 + rr) * 2 + jj] = o;
  }
}

// ---------------- GCN graph-operator precompute (fused, no global atomics) --
// Edges are grouped by graph (e = g*88 + j), so degrees and M are block-local.
__global__ __launch_bounds__(256) void k_graph_mats(const int* __restrict__ src,
                                                    const int* __restrict__ dst,
                                                    float* __restrict__ Mg) {
  constexpr int GPB = 32;                 // graphs per block
  __shared__ float Ms[GPB * 121];
  __shared__ float od[GPB * NPG];
  __shared__ float idg[GPB * NPG];
  const int tid = threadIdx.x;
  const int g0 = blockIdx.x * GPB;
  for (int i = tid; i < GPB * 121; i += 256) Ms[i] = 0.f;
  for (int i = tid; i < GPB * NPG; i += 256) { od[i] = 0.f; idg[i] = 0.f; }
  __syncthreads();
  const int ebase = g0 * 88;              // 32*88 = 2816 = 11*256 edges
  int ls[11], ld[11];
  #pragma unroll
  for (int i = 0; i < 11; ++i) {
    const int e = ebase + tid + i * 256;
    const int s = src[e], d = dst[e];
    const int g = s / NPG;                // src and dst share the graph
    const int gl = g - g0;
    ls[i] = gl * NPG + (s - g * NPG);
    ld[i] = gl * NPG + (d - g * NPG);
    atomicAdd(&od[ls[i]], 1.f);
    atomicAdd(&idg[ld[i]], 1.f);
  }
  __syncthreads();
  for (int i = tid; i < GPB * NPG; i += 256) {
    od[i]  = rsqrtf(fmaxf(od[i], 1.f));
    idg[i] = rsqrtf(fmaxf(idg[i], 1.f));
  }
  __syncthreads();
  #pragma unroll
  for (int i = 0; i < 11; ++i) {
    const int gl  = ls[i] / NPG;
    const int lsl = ls[i] - gl * NPG;
    const int ldl = ld[i] - gl * NPG;
    atomicAdd(&Ms[gl * 121 + ldl * NPG + lsl], od[ls[i]] * idg[ld[i]]);
  }
  __syncthreads();
  for (int i = tid; i < GPB * 121; i += 256) Mg[(size_t)g0 * 121 + i] = Ms[i];
}

// X[g,d,:] = act( sum_s M_g[d][s] * Y[g,s,:] + bias )  in-place safe
template<int ACT>
__global__ __launch_bounds__(256) void k_mapply(const u16* __restrict__ Y,
                                                const float* __restrict__ Mg,
                                                const float* __restrict__ bias,
                                                u16* __restrict__ X) {
  __shared__ float Ms[121];
  const int g = blockIdx.x, c = threadIdx.x;
  if (c < 121) Ms[c] = Mg[(size_t)g * 121 + c];
  float y[NPG];
  const u16* yp = Y + (size_t)g * NPG * 256 + c;
  #pragma unroll
  for (int s = 0; s < NPG; ++s) y[s] = bf2f(yp[s * 256]);
  const float bc_ = bias[c];
  __syncthreads();
  u16* xp = X + (size_t)g * NPG * 256 + c;
  #pragma unroll
  for (int d = 0; d < NPG; ++d) {
    float z = bc_;
    #pragma unroll
    for (int s = 0; s < NPG; ++s) z += Ms[d * NPG + s] * y[s];
    if (ACT == 0) z = fmaxf(z, 0.f); else z = fast_tanh(z);
    xp[d * 256] = f2bf(z);
  }
}

// Y3[N,8] = X[N,256] @ W3[256,8]
__global__ __launch_bounds__(256) void k_gemm3(const u16* __restrict__ X,
                                               const float* __restrict__ W3,
                                               float* __restrict__ Y3) {
  __shared__ float W3s[2048];
  const int tid = threadIdx.x;
  for (int i = tid; i < 2048; i += 256) W3s[i] = W3[i];
  __syncthreads();
  const int r = tid >> 3, j = tid & 7;
  const int row = blockIdx.x * 32 + r;
  const u16* xp = X + (size_t)row * 256;
  float acc = 0.f;
  #pragma unroll 4
  for (int k = 0; k < 256; ++k) acc += bf2f(xp[k]) * W3s[k * 8 + j];
  Y3[(size_t)row * 8 + j] = acc;
}

// layer3 M-apply + relu + mean + classify + add LSTM ff output
__global__ __launch_bounds__(256) void k_final(const float* __restrict__ Y3,
                                               const float* __restrict__ Mg,
                                               const float* __restrict__ b3,
                                               const float* __restrict__ Wc,
                                               const float* __restrict__ bc,
                                               const float* __restrict__ ffout,
                                               float* __restrict__ out) {
  __shared__ float Ms[32][121];
  __shared__ float hg[32][8];
  const int tid = threadIdx.x;
  const int g0 = blockIdx.x * 32;
  for (int i = tid; i < 32 * 121; i += 256) Ms[i / 121][i % 121] = Mg[(size_t)g0 * 121 + i];
  const int gl = tid >> 3, j = tid & 7;
  const int g = g0 + gl;
  float y[NPG];
  #pragma unroll
  for (int s = 0; s < NPG; ++s) y[s] = Y3[((size_t)g * NPG + s) * 8 + j];
  __syncthreads();
  const float bj = b3[j];
  float accm = 0.f;
  #pragma unroll
  for (int d = 0; d < NPG; ++d) {
    float z = bj;
    #pragma unroll
    for (int s = 0; s < NPG; ++s) z += Ms[gl][d * NPG + s] * y[s];
    accm += fmaxf(z, 0.f);
  }
  hg[gl][j] = accm * (1.0f / 11.0f);
  __syncthreads();
  if (j < 2) {
    float o = bc[j];
    #pragma unroll
    for (int qq = 0; qq < 8; ++qq) o += hg[gl][qq] * Wc[qq * 2 + j];
    out[(size_t)g * 2 + j] = o + ffout[(size_t)g * 2 + j];
  }
}

// ---------------------------------------------------------------------------
extern "C" void kernel_launch(void* const* d_in, const int* in_sizes, int n_in,
                              void* d_out, int out_size, void* d_ws, size_t ws_size,
                              hipStream_t stream) {
  (void)in_sizes; (void)n_in; (void)out_size; (void)ws_size;
  const float* feature = (const float*)d_in[0];
  const int*   src     = (const int*)d_in[1];
  const int*   dst     = (const int*)d_in[2];
  const float* W1  = (const float*)d_in[3];
  const float* b1  = (const float*)d_in[4];
  const float* W2  = (const float*)d_in[5];
  const float* b2  = (const float*)d_in[6];
  const float* W3  = (const float*)d_in[7];
  const float* b3  = (const float*)d_in[8];
  const float* Wih = (const float*)d_in[9];
  const float* Whh = (const float*)d_in[10];
  const float* bih = (const float*)d_in[11];
  const float* bhh = (const float*)d_in[12];
  const float* Wf1 = (const float*)d_in[13];
  const float* bf1 = (const float*)d_in[14];
  const float* Wf2 = (const float*)d_in[15];
  const float* bf2 = (const float*)d_in[16];
  const float* Wc  = (const float*)d_in[17];
  const float* bc  = (const float*)d_in[18];
  float* out = (float*)d_out;

  // ---- workspace layout: 107,417,600 B total (unchanged from passing R2) ---
  char* ws = (char*)d_ws;
  float* ffout = (float*)ws;                        //    131,072
  u16*   WfP   = (u16*)(ws + 131072);               //  1,048,576
  u16*   Wt1   = (u16*)(ws + 1179648);              //    131,072
  u16*   Wt2   = (u16*)(ws + 1310720);              //    131,072
  float* biasP = (float*)(ws + 1441792);            //      4,096
  float* Mg    = (float*)(ws + 1445888);            //  7,929,856
  u16*   Abuf  = (u16*)(ws + 9375744);              // 92,274,688
  u16*   hbuf  = (u16*)(ws + 9375744);              //  8,388,608 (alias, LSTM phase only)
  float* Y3    = (float*)(ws + 101650432);          //  5,767,168

  // ---- weight prep ----
  k_prep_lstm_w<<<2048, 256, 0, stream>>>(Wih, Whh, bih, bhh, WfP, biasP);
  k_transpose_w<<<256, 256, 0, stream>>>(W1, Wt1);
  k_transpose_w<<<256, 256, 0, stream>>>(W2, Wt2);

  // ================= LSTM branch (single persistent kernel) =================
  lstm_all<<<BG / 64, 1024, 0, stream>>>(feature, hbuf, WfP, biasP);
  ff_kernel<<<BG / 16, 256, 0, stream>>>(hbuf, Wf1, bf1, Wf2, bf2, ffout);
  // hbuf dead from here on; Abuf may now overwrite it.

  // ================= GCN branch =================
  k_graph_mats<<<BG / 32, 256, 0, stream>>>(src, dst, Mg);

  // layer 1: GEMM (fp32 A -> bf16) + in-place graph mix + relu
  gemm_mfma<0, u16><<<dim3(1, NTOT / 128), 512, 0, stream>>>(feature, nullptr, Wt1, Abuf, 256, 256);
  k_mapply<0><<<BG, 256, 0, stream>>>(Abuf, Mg, b1, Abuf);

  // layer 2: in-place GEMM (full N covered per row-block) + mix + tanh
  gemm_mfma<1, u16><<<dim3(1, NTOT / 128), 512, 0, stream>>>(nullptr, Abuf, Wt2, Abuf, 256, 256);
  k_mapply<1><<<BG, 256, 0, stream>>>(Abuf, Mg, b2, Abuf);

  // layer 3 + pooling + classifier + combine
  k_gemm3<<<NTOT / 32, 256, 0, stream>>>(Abuf, W3, Y3);
  k_final<<<BG / 32, 256, 0, stream>>>(Y3, Mg, b3, Wc, bc, ffout, out);
}